// Round 7
// baseline (3360.785 us; speedup 1.0000x reference)
//
#include <hip/hip_runtime.h>
#include <cstdint>

// FPS: B=8, N=131072, NPOINT=1024.  Exact-index replication of the jax reference.
//
// v7: proven v0 protocol (16 blocks/batch, 1024 thr, one barrier/round, LDS
// atomic-max fan-in, monotone tag-packed keys, parity dbuf, agent-scope slot
// exchange -- the L2 fast path was proven DEAD in v6 and is gone) with two
// mechanical upgrades to the measured bottleneck (detect latency):
//   1) PIPELINED POLLING: inline-asm loop keeps 4 outstanding slot loads per
//      lane (s_waitcnt vmcnt(3) rotation) -> slot sampled every ~1/4 MALL
//      latency instead of every full latency; block exit = max over 16 waves'
//      sampling phases, so 4x sampling also shrinks the max-penalty.
//      Exact-tag check (v_lshrrev_b64 49 + v_cmp_eq_u64) -- poison tag 0x2AAA
//      never matches a live round, old parities fail equality. vmcnt drained
//      on entry (post store!) and exit so the vmcnt(3) accounting is exact.
//   2) 64B-PADDED SLOTS: the 16 posts of a batch land in 16 distinct cache
//      lines -> no line serialization at the coherence point.
// Packed key u64: [t:15][fp32 dist bits:32][(~idx)&0x1FFFF:17] -> unsigned max
// == (round, dist desc, idx asc) == np.argmax first-max tie-break.

constexpr int kB = 8;
constexpr int kN = 131072;
constexpr int kNpoint = 1024;
constexpr int kBlocksPerBatch = 16;
constexpr int kThreads = 1024;
constexpr int kPPT = 8;
constexpr int kPtsPerBlock = kThreads * kPPT;  // 8192
constexpr int kSlotPad = 8;                    // u64 per slot = 64 B line

typedef float f32x2 __attribute__((ext_vector_type(2)));

__device__ __forceinline__ uint64_t u64max(uint64_t a, uint64_t b) {
    return a > b ? a : b;
}

// DPP move of a u64 (both halves, same ctrl); invalid source lanes yield 0,
// the identity for our non-negative packed keys.
template <int CTRL>
__device__ __forceinline__ uint64_t dpp_u64(uint64_t v) {
    int lo = __builtin_amdgcn_update_dpp(0, (int)(uint32_t)v, CTRL, 0xF, 0xF, false);
    int hi = __builtin_amdgcn_update_dpp(0, (int)(uint32_t)(v >> 32), CTRL, 0xF, 0xF, false);
    return ((uint64_t)(uint32_t)hi << 32) | (uint32_t)lo;
}

// Full-wave max; result valid in lane 63 (row_shr/row_bcast ladder).
__device__ __forceinline__ uint64_t wave_max_to_lane63(uint64_t v) {
    v = u64max(v, dpp_u64<0x111>(v));  // row_shr:1
    v = u64max(v, dpp_u64<0x112>(v));  // row_shr:2
    v = u64max(v, dpp_u64<0x114>(v));  // row_shr:4
    v = u64max(v, dpp_u64<0x118>(v));  // row_shr:8
    v = u64max(v, dpp_u64<0x142>(v));  // row_bcast:15
    v = u64max(v, dpp_u64<0x143>(v));  // row_bcast:31
    return v;
}

__device__ __forceinline__ void st_u64_agent(uint64_t* p, uint64_t v) {
    __hip_atomic_store(p, v, __ATOMIC_RELAXED, __HIP_MEMORY_SCOPE_AGENT);
}

// Pipelined slot poll: 4 outstanding loads, rotate via s_waitcnt vmcnt(3).
// All 64 lanes participate (lane polls p = its slot; 4 lanes per slot).
// Exits when EVERY lane's sampled value has tag == t. Returns the matched
// value.  Entry drains vmcnt (the poster's store is outstanding in the same
// wave!); exit drains the 3 leftover speculative loads.
__device__ __forceinline__ uint64_t poll_pipelined(const uint64_t* p, uint64_t texp) {
    uint64_t r0, r1, r2, r3, tm, out, sA;
    asm volatile(
        "s_waitcnt vmcnt(0)\n\t"
        "global_load_dwordx2 %[r0], %[p], off sc0 sc1\n\t"
        "global_load_dwordx2 %[r1], %[p], off sc0 sc1\n\t"
        "global_load_dwordx2 %[r2], %[p], off sc0 sc1\n\t"
        "global_load_dwordx2 %[r3], %[p], off sc0 sc1\n\t"
        "1:\n\t"
        "s_waitcnt vmcnt(3)\n\t"                    // r0 ready
        "v_lshrrev_b64 %[tm], 49, %[r0]\n\t"
        "v_cmp_eq_u64 vcc, %[tx], %[tm]\n\t"
        "s_andn2_b64 %[sA], exec, vcc\n\t"          // SCC = any lane unmatched
        "s_cbranch_scc0 20f\n\t"
        "global_load_dwordx2 %[r0], %[p], off sc0 sc1\n\t"
        "s_waitcnt vmcnt(3)\n\t"                    // r1 ready
        "v_lshrrev_b64 %[tm], 49, %[r1]\n\t"
        "v_cmp_eq_u64 vcc, %[tx], %[tm]\n\t"
        "s_andn2_b64 %[sA], exec, vcc\n\t"
        "s_cbranch_scc0 21f\n\t"
        "global_load_dwordx2 %[r1], %[p], off sc0 sc1\n\t"
        "s_waitcnt vmcnt(3)\n\t"                    // r2 ready
        "v_lshrrev_b64 %[tm], 49, %[r2]\n\t"
        "v_cmp_eq_u64 vcc, %[tx], %[tm]\n\t"
        "s_andn2_b64 %[sA], exec, vcc\n\t"
        "s_cbranch_scc0 22f\n\t"
        "global_load_dwordx2 %[r2], %[p], off sc0 sc1\n\t"
        "s_waitcnt vmcnt(3)\n\t"                    // r3 ready
        "v_lshrrev_b64 %[tm], 49, %[r3]\n\t"
        "v_cmp_eq_u64 vcc, %[tx], %[tm]\n\t"
        "s_andn2_b64 %[sA], exec, vcc\n\t"
        "s_cbranch_scc0 23f\n\t"
        "global_load_dwordx2 %[r3], %[p], off sc0 sc1\n\t"
        "s_branch 1b\n\t"
        "20:\n\t" "v_lshrrev_b64 %[out], 0, %[r0]\n\t" "s_branch 9f\n\t"
        "21:\n\t" "v_lshrrev_b64 %[out], 0, %[r1]\n\t" "s_branch 9f\n\t"
        "22:\n\t" "v_lshrrev_b64 %[out], 0, %[r2]\n\t" "s_branch 9f\n\t"
        "23:\n\t" "v_lshrrev_b64 %[out], 0, %[r3]\n\t"
        "9:\n\t"
        "s_waitcnt vmcnt(0)\n\t"                    // drain speculative loads
        : [r0]"=&v"(r0), [r1]"=&v"(r1), [r2]"=&v"(r2), [r3]"=&v"(r3),
          [tm]"=&v"(tm), [out]"=&v"(out), [sA]"=&s"(sA)
        : [p]"v"(p), [tx]"v"(texp)
        : "vcc", "scc", "memory");
    return out;
}

__global__ __launch_bounds__(kThreads, 4) void fps_kernel(
        const float* __restrict__ xyz, float* __restrict__ out,
        uint64_t* __restrict__ slots) {
#pragma clang fp contract(off)
    const int b    = blockIdx.x & 7;    // batch
    const int blk  = blockIdx.x >> 3;   // block within batch, 0..15
    const int tid  = threadIdx.x;
    const int lane = tid & 63;

    const float* __restrict__ base = xyz + (size_t)b * kN * 3;

    // Register-resident state as packed pairs: .x is point j=2q, .y is j=2q+1
    // (ascending index order preserved for the first-max tie-break).
    f32x2 X[4], Y[4], Z[4], MD[4];
#pragma unroll
    for (int q = 0; q < 4; ++q) {
        const int p0 = blk * kPtsPerBlock + (2 * q) * kThreads + tid;
        const int p1 = p0 + kThreads;
        X[q].x = base[3 * p0 + 0]; X[q].y = base[3 * p1 + 0];
        Y[q].x = base[3 * p0 + 1]; Y[q].y = base[3 * p1 + 1];
        Z[q].x = base[3 * p0 + 2]; Z[q].y = base[3 * p1 + 2];
        MD[q].x = __builtin_inff(); MD[q].y = __builtin_inff();
    }

    __shared__ uint64_t lbest[2];
    if (tid == 0) { lbest[0] = 0; lbest[1] = 0; }

    // First sample is always point 0.
    float cx = base[0], cy = base[1], cz = base[2];
    if (blk == 0 && tid == 0) {
        float* o = out + (size_t)b * kNpoint * 3;
        o[0] = cx; o[1] = cy; o[2] = cz;
    }
    __syncthreads();  // lbest init visible

    for (int t = 1; t < kNpoint; ++t) {
        // --- mindist update + per-thread argmax (exact fp32, no contraction) ---
        const f32x2 vcx = {cx, cx}, vcy = {cy, cy}, vcz = {cz, cz};
        float bm = -1.0f;
        int   bj = 0;
#pragma unroll
        for (int q = 0; q < 4; ++q) {
            const f32x2 dx = X[q] - vcx;
            const f32x2 dy = Y[q] - vcy;
            const f32x2 dz = Z[q] - vcz;
            const f32x2 d  = (dx * dx + dy * dy) + dz * dz;  // (xx+yy)+zz, RN
            f32x2 m;
            m.x = fminf(MD[q].x, d.x);
            m.y = fminf(MD[q].y, d.y);
            MD[q] = m;
            // .x is the smaller index -- evaluate first; strict > keeps first max
            const bool g0 = m.x > bm;  bj = g0 ? (2 * q)     : bj;  bm = g0 ? m.x : bm;
            const bool g1 = m.y > bm;  bj = g1 ? (2 * q + 1) : bj;  bm = g1 ? m.y : bm;
        }
        const uint32_t p = (uint32_t)(blk * kPtsPerBlock + bj * kThreads + tid);
        uint64_t pk = ((uint64_t)t << 49) |
                      ((uint64_t)__float_as_uint(bm) << 17) |
                      ((~p) & 0x1FFFFu);

        // --- wave max -> lane 63 -> LDS atomic max (tag-packed, parity dbuf) ---
        pk = wave_max_to_lane63(pk);
        if (lane == 63) {
            __hip_atomic_fetch_max(&lbest[t & 1], pk, __ATOMIC_RELAXED,
                                   __HIP_MEMORY_SCOPE_WORKGROUP);
        }
        __syncthreads();  // the one barrier: block best complete in LDS

        uint64_t* const slotbuf =
                slots + ((size_t)(t & 1) * kB + b) * kBlocksPerBatch * kSlotPad;
        if (tid == 0) {
            // already tagged with t; single-u64 payload -> relaxed suffices
            st_u64_agent(&slotbuf[(size_t)blk * kSlotPad], lbest[t & 1]);
        }

        // --- every wave: pipelined poll (4 outstanding loads, exact tags) ---
        const uint64_t got =
                poll_pipelined(&slotbuf[(size_t)(lane & 15) * kSlotPad], (uint64_t)t);

        // full-wave max (all 16-lane groups identical) -> lane 63 -> scalar bcast
        const uint64_t wk = wave_max_to_lane63(got);
        const uint32_t wlo = (uint32_t)__builtin_amdgcn_readlane((int)(uint32_t)wk, 63);
        const uint32_t widx = 131071u - (wlo & 0x1FFFFu);
        cx = base[3 * (size_t)widx + 0];
        cy = base[3 * (size_t)widx + 1];
        cz = base[3 * (size_t)widx + 2];
        if (blk == 0 && tid == 0) {
            float* o = out + ((size_t)b * kNpoint + t) * 3;
            o[0] = cx; o[1] = cy; o[2] = cz;
        }
    }
}

extern "C" void kernel_launch(void* const* d_in, const int* in_sizes, int n_in,
                              void* d_out, int out_size, void* d_ws, size_t ws_size,
                              hipStream_t stream) {
    const float* xyz = (const float*)d_in[0];
    float* out = (float*)d_out;
    uint64_t* slots = (uint64_t*)d_ws;  // 2 * 8 * 16 * 8 u64 = 16 KiB used
    fps_kernel<<<dim3(kB * kBlocksPerBatch), dim3(kThreads), 0, stream>>>(xyz, out, slots);
}

// Round 8
// 2820.262 us; speedup vs baseline: 1.1917x; 1.1917x over previous
//
#include <hip/hip_runtime.h>
#include <cstdint>

// FPS: B=8, N=131072, NPOINT=1024.  Exact-index replication of the jax reference.
//
// v8: three latency trims on the proven v0 protocol, all using mechanisms
// individually validated in earlier rounds:
//   1) DIRECT WAVE POSTS: lane 63 of EVERY wave agent-stores its wave winner
//      (already round-tagged) to slot[b][t&1][blk*16+wave] right after the
//      DPP ladder. Deletes the serialized LDS-atomic fan-in and the pre-post
//      barrier from the post path (~400cy) and moves posts earlier.
//      Slot-reuse safety: a t+2 post requires passing barrier(t+1), which
//      requires this block's wave0 poll(t+1) to have seen every wave's t+1
//      post; any block's t+1 posts postdate its barrier(t), i.e. its wave0's
//      completed poll(t). So nobody can still be polling round t when a t+2
//      (same parity) post lands. Monotone tags + parity dbuf as before.
//   2) SINGLE POLLER, 2-DEEP: only wave 0 polls (v3 proved safe/neutral),
//      4 slots/lane x 2 batches in flight = 512 loads/block -- inside the
//      proven-safe traffic dose (v7's 4096 choked the MALL, tripling FETCH).
//      Sampling period ~RT/2 -> detect phase roughly halves.
//   3) LDS BROADCAST EPILOGUE (v3-proven): wave 0 reduces 256 keys, 3 lanes
//      fetch winner coords (one cached line), write parity LDS cells bc[t&1];
//      waves 1-15 sleep at the single per-round __syncthreads.
// Packed key u64: [t:15][fp32 dist bits:32][(~idx)&0x1FFFF:17] -> unsigned max
// == (round, dist desc, idx asc) == np.argmax first-max tie-break.  Poisoned
// workspace (0x5555...) has tag 0x2AAA > 1023: never matches a live round.

constexpr int kB = 8;
constexpr int kN = 131072;
constexpr int kNpoint = 1024;
constexpr int kBlocksPerBatch = 16;
constexpr int kThreads = 1024;
constexpr int kWaves = kThreads / 64;                    // 16
constexpr int kSlotsPerBatch = kBlocksPerBatch * kWaves; // 256
constexpr int kPPT = 8;
constexpr int kPtsPerBlock = kThreads * kPPT;            // 8192

typedef float f32x2 __attribute__((ext_vector_type(2)));

__device__ __forceinline__ uint64_t u64max(uint64_t a, uint64_t b) {
    return a > b ? a : b;
}

// DPP move of a u64 (both halves, same ctrl); invalid source lanes yield 0,
// the identity for our non-negative packed keys.
template <int CTRL>
__device__ __forceinline__ uint64_t dpp_u64(uint64_t v) {
    int lo = __builtin_amdgcn_update_dpp(0, (int)(uint32_t)v, CTRL, 0xF, 0xF, false);
    int hi = __builtin_amdgcn_update_dpp(0, (int)(uint32_t)(v >> 32), CTRL, 0xF, 0xF, false);
    return ((uint64_t)(uint32_t)hi << 32) | (uint32_t)lo;
}

// Full-wave max; result valid in lane 63 (row_shr/row_bcast ladder).
__device__ __forceinline__ uint64_t wave_max_to_lane63(uint64_t v) {
    v = u64max(v, dpp_u64<0x111>(v));  // row_shr:1
    v = u64max(v, dpp_u64<0x112>(v));  // row_shr:2
    v = u64max(v, dpp_u64<0x114>(v));  // row_shr:4
    v = u64max(v, dpp_u64<0x118>(v));  // row_shr:8
    v = u64max(v, dpp_u64<0x142>(v));  // row_bcast:15
    v = u64max(v, dpp_u64<0x143>(v));  // row_bcast:31
    return v;
}

__device__ __forceinline__ uint64_t ld_u64_agent(const uint64_t* p) {
    return __hip_atomic_load(p, __ATOMIC_RELAXED, __HIP_MEMORY_SCOPE_AGENT);
}
__device__ __forceinline__ void st_u64_agent(uint64_t* p, uint64_t v) {
    __hip_atomic_store(p, v, __ATOMIC_RELAXED, __HIP_MEMORY_SCOPE_AGENT);
}

__global__ __launch_bounds__(kThreads, 4) void fps_kernel(
        const float* __restrict__ xyz, float* __restrict__ out,
        uint64_t* __restrict__ slots) {
#pragma clang fp contract(off)
    const int b    = blockIdx.x & 7;    // batch
    const int blk  = blockIdx.x >> 3;   // block within batch, 0..15
    const int tid  = threadIdx.x;
    const int lane = tid & 63;
    const int wave = tid >> 6;                 // 0..15
    const int wslot = blk * kWaves + wave;     // 0..255 within batch

    const float* __restrict__ base = xyz + (size_t)b * kN * 3;

    // Register-resident state as packed pairs: .x is point j=2q, .y is j=2q+1
    // (ascending index order preserved for the first-max tie-break).
    f32x2 X[4], Y[4], Z[4], MD[4];
#pragma unroll
    for (int q = 0; q < 4; ++q) {
        const int p0 = blk * kPtsPerBlock + (2 * q) * kThreads + tid;
        const int p1 = p0 + kThreads;
        X[q].x = base[3 * p0 + 0]; X[q].y = base[3 * p1 + 0];
        Y[q].x = base[3 * p0 + 1]; Y[q].y = base[3 * p1 + 1];
        Z[q].x = base[3 * p0 + 2]; Z[q].y = base[3 * p1 + 2];
        MD[q].x = __builtin_inff(); MD[q].y = __builtin_inff();
    }

    __shared__ float bc[2][3];

    // First sample is always point 0.
    float cx = base[0], cy = base[1], cz = base[2];
    if (blk == 0 && tid == 0) {
        float* o = out + (size_t)b * kNpoint * 3;
        o[0] = cx; o[1] = cy; o[2] = cz;
    }

    for (int t = 1; t < kNpoint; ++t) {
        // --- mindist update + per-thread argmax (exact fp32, no contraction) ---
        const f32x2 vcx = {cx, cx}, vcy = {cy, cy}, vcz = {cz, cz};
        float bm = -1.0f;
        int   bj = 0;
#pragma unroll
        for (int q = 0; q < 4; ++q) {
            const f32x2 dx = X[q] - vcx;
            const f32x2 dy = Y[q] - vcy;
            const f32x2 dz = Z[q] - vcz;
            const f32x2 d  = (dx * dx + dy * dy) + dz * dz;  // (xx+yy)+zz, RN
            f32x2 m;
            m.x = fminf(MD[q].x, d.x);
            m.y = fminf(MD[q].y, d.y);
            MD[q] = m;
            // .x is the smaller index -- evaluate first; strict > keeps first max
            const bool g0 = m.x > bm;  bj = g0 ? (2 * q)     : bj;  bm = g0 ? m.x : bm;
            const bool g1 = m.y > bm;  bj = g1 ? (2 * q + 1) : bj;  bm = g1 ? m.y : bm;
        }
        const uint32_t p = (uint32_t)(blk * kPtsPerBlock + bj * kThreads + tid);
        const uint64_t mykey = ((uint64_t)t << 49) |
                               ((uint64_t)__float_as_uint(bm) << 17) |
                               ((~p) & 0x1FFFFu);

        // --- wave ladder -> lane 63 posts the wave winner DIRECTLY ---
        const uint64_t wk = wave_max_to_lane63(mykey);
        uint64_t* const slotbuf =
                slots + ((size_t)(t & 1) * kB + b) * kSlotsPerBatch;
        if (lane == 63) {
            st_u64_agent(&slotbuf[wslot], wk);  // already tagged with t
        }

        // --- wave 0 polls all 256 slots: 4/lane, 2 batches in flight ---
        if (wave == 0) {
            const uint64_t tt = (uint64_t)t;
            const uint64_t* const s0 = &slotbuf[lane];
            uint64_t r0, r1, r2, r3;
            // batch A issued; loop alternates issue/check so ~8 loads stay
            // in flight per lane (512/block -- proven-safe traffic dose).
            uint64_t a0 = ld_u64_agent(s0 + 0),   a1 = ld_u64_agent(s0 + 64),
                     a2 = ld_u64_agent(s0 + 128), a3 = ld_u64_agent(s0 + 192);
            for (;;) {
                uint64_t b0 = ld_u64_agent(s0 + 0),   b1 = ld_u64_agent(s0 + 64),
                         b2 = ld_u64_agent(s0 + 128), b3 = ld_u64_agent(s0 + 192);
                const bool okA = ((a0 >> 49) == tt) & ((a1 >> 49) == tt) &
                                 ((a2 >> 49) == tt) & ((a3 >> 49) == tt);
                if (__all(okA)) { r0 = a0; r1 = a1; r2 = a2; r3 = a3; break; }
                a0 = ld_u64_agent(s0 + 0);   a1 = ld_u64_agent(s0 + 64);
                a2 = ld_u64_agent(s0 + 128); a3 = ld_u64_agent(s0 + 192);
                const bool okB = ((b0 >> 49) == tt) & ((b1 >> 49) == tt) &
                                 ((b2 >> 49) == tt) & ((b3 >> 49) == tt);
                if (__all(okB)) { r0 = b0; r1 = b1; r2 = b2; r3 = b3; break; }
            }
            // reduce 4 -> wave ladder -> scalar winner index
            uint64_t m = u64max(u64max(r0, r1), u64max(r2, r3));
            m = wave_max_to_lane63(m);
            const uint32_t wlo = (uint32_t)__builtin_amdgcn_readlane((int)(uint32_t)m, 63);
            const uint32_t widx = 131071u - (wlo & 0x1FFFFu);  // uniform
            if (lane < 3) {
                // one cached line; 3 lanes in parallel
                const float v = base[3 * (size_t)widx + lane];
                bc[t & 1][lane] = v;
                if (blk == 0) out[((size_t)b * kNpoint + t) * 3 + lane] = v;
            }
        }
        __syncthreads();  // the one barrier per round; bc parity dbuf race-free
        cx = bc[t & 1][0];
        cy = bc[t & 1][1];
        cz = bc[t & 1][2];
    }
}

extern "C" void kernel_launch(void* const* d_in, const int* in_sizes, int n_in,
                              void* d_out, int out_size, void* d_ws, size_t ws_size,
                              hipStream_t stream) {
    const float* xyz = (const float*)d_in[0];
    float* out = (float*)d_out;
    uint64_t* slots = (uint64_t*)d_ws;  // 2 * 8 * 256 u64 = 32 KiB used
    fps_kernel<<<dim3(kB * kBlocksPerBatch), dim3(kThreads), 0, stream>>>(xyz, out, slots);
}